// Round 5
// baseline (423.885 us; speedup 1.0000x reference)
//
#include <hip/hip_runtime.h>
#include <hip/hip_bf16.h>
#include <math.h>

#define B_ 16
#define C_ 64
#define H_ 128
#define W_ 128
#define HW_ (H_*W_)
#define CHW_ (C_*HW_)
#define NTOT_ (B_*CHW_)

typedef __attribute__((ext_vector_type(8))) short short8;
typedef __attribute__((ext_vector_type(4))) float float4v;

__device__ __forceinline__ float leaky(float v) { return v > 0.f ? v : 0.1f * v; }
__device__ __forceinline__ float b2f(__hip_bfloat16 h) { return __bfloat162float(h); }

// ---------------------------------------------------------------------------
// Dynamic kernel MLPs, wide: 96 blocks (2 which x 16 b x 3 chunks of 192).
// out layout: kern[b][t][c] for lane=c access in k_rda.
// ---------------------------------------------------------------------------
__global__ __launch_bounds__(192) void k_dyn(
    const float* __restrict__ d,
    const float* __restrict__ k1a, const float* __restrict__ k2a,
    const float* __restrict__ k1b, const float* __restrict__ k2b,
    float* __restrict__ kernA, float* __restrict__ kernB)
{
    const int which = blockIdx.x / 48;
    const int r     = blockIdx.x % 48;
    const int b     = r / 3;
    const int chunk = r % 3;
    const float* k1 = which ? k1b : k1a;
    const float* k2 = which ? k2b : k2a;
    float* outp = which ? kernB : kernA;

    __shared__ float hid[64];
    const int tid = threadIdx.x;
    if (tid < 64) {
        float s = 0.f;
        #pragma unroll
        for (int i = 0; i < 64; ++i) s = fmaf(d[b*64 + i], k1[i*64 + tid], s);
        hid[tid] = leaky(s);
    }
    __syncthreads();
    const int o = chunk * 192 + tid;       // 0..575
    float s = 0.f;
    #pragma unroll
    for (int j = 0; j < 64; ++j) s = fmaf(hid[j], k2[j*576 + o], s);
    outp[b*576 + (o % 9)*64 + (o / 9)] = s;
}

// ---------------------------------------------------------------------------
// Prepack conv weights: Wpk[s][oc][kk] bf16, s = t*2 + half, k = half*32+kk.
// ---------------------------------------------------------------------------
__global__ void k_prepw(const float* __restrict__ W1, const float* __restrict__ W2,
                        __hip_bfloat16* __restrict__ P1, __hip_bfloat16* __restrict__ P2)
{
    const int s = blockIdx.x;      // 0..17
    const int which = blockIdx.y;  // 0..1
    const float* W = which ? W2 : W1;
    __hip_bfloat16* P = which ? P2 : P1;
    const int t = s >> 1, half = s & 1;
    for (int idx = threadIdx.x; idx < 2048; idx += 256) {
        const int oc = idx >> 5, kk = idx & 31;
        P[s*2048 + idx] = __float2bfloat16(W[oc*576 + (half*32 + kk)*9 + t]);
    }
}

// ---------------------------------------------------------------------------
// NCHW fp32 -> NHWC bf16 + fused rda1 gate: G1[p] = sigmoid(sum_c x*cw + cb).
// grid (HW/64, B), block 256.
// ---------------------------------------------------------------------------
__global__ __launch_bounds__(256) void k_pre(const float* __restrict__ X,
                                             const float* __restrict__ cw,
                                             const float* __restrict__ cb,
                                             __hip_bfloat16* __restrict__ Xn,
                                             float* __restrict__ G1)
{
    __shared__ float sT[64][65];
    __shared__ float pG[4][64];
    const int b = blockIdx.y;
    const int p0 = blockIdx.x * 64;
    const int tid = threadIdx.x;
    #pragma unroll
    for (int i = 0; i < 16; ++i) {
        int idx = i*256 + tid;
        int c = idx >> 6, p = idx & 63;
        sT[c][p] = X[(size_t)b*CHW_ + (size_t)c*HW_ + p0 + p];
    }
    __syncthreads();
    #pragma unroll
    for (int i = 0; i < 16; ++i) {
        int idx = i*256 + tid;
        int p = idx >> 6, c = idx & 63;
        Xn[((size_t)b*HW_ + p0 + p)*64 + c] = __float2bfloat16(sT[c][p]);
    }
    const int cg = tid >> 6, p = tid & 63;
    float part = 0.f;
    #pragma unroll
    for (int c = 0; c < 16; ++c) part = fmaf(sT[cg*16 + c][p], cw[cg*16 + c], part);
    pG[cg][p] = part;
    __syncthreads();
    if (tid < 64) {
        float g = pG[0][tid] + pG[1][tid] + pG[2][tid] + pG[3][tid] + cb[0];
        G1[(size_t)b*HW_ + p0 + tid] = 1.f / (1.f + __expf(-g));
    }
}

// ---------------------------------------------------------------------------
// Fused RDA in NHWC, rolling-window. lane = channel; wave = 8 px row segment.
// out = leaky( leaky(dw3x3(X)) * G + X ).  grid = B*HW/32 blocks of 256.
// ---------------------------------------------------------------------------
__global__ __launch_bounds__(256) void k_rda_nhwc(
    const __hip_bfloat16* __restrict__ Xn, const float* __restrict__ kernN,
    const float* __restrict__ G, __hip_bfloat16* __restrict__ Out)
{
    const int lane = threadIdx.x & 63;
    const int wv = threadIdx.x >> 6;
    const int gid = blockIdx.x * 4 + wv;
    const int b = gid >> 11;
    const int rem = gid & 2047;
    const int h = rem >> 4;
    const int w0 = (rem & 15) * 8;

    float k9[9];
    #pragma unroll
    for (int t = 0; t < 9; ++t) k9[t] = kernN[((size_t)b*9 + t)*64 + lane];

    const __hip_bfloat16* Xb = Xn + (size_t)b * HW_ * 64 + lane;
    float r[3][10];
    #pragma unroll
    for (int dh = 0; dh < 3; ++dh) {
        const int hh = h - 1 + dh;
        if ((unsigned)hh < (unsigned)H_) {
            const __hip_bfloat16* rp = Xb + ((size_t)hh*W_ + w0) * 64;
            r[dh][0] = (w0 > 0) ? b2f(rp[-64]) : 0.f;
            #pragma unroll
            for (int j = 1; j < 9; ++j) r[dh][j] = b2f(rp[(j-1)*64]);
            r[dh][9] = (w0 + 8 < W_) ? b2f(rp[8*64]) : 0.f;
        } else {
            #pragma unroll
            for (int j = 0; j < 10; ++j) r[dh][j] = 0.f;
        }
    }

    const float* Gp = G + (size_t)b*HW_ + (size_t)h*W_ + w0;
    __hip_bfloat16* Op = Out + ((size_t)b*HW_ + (size_t)h*W_ + w0)*64 + lane;
    #pragma unroll
    for (int i = 0; i < 8; ++i) {
        float s = 0.f;
        #pragma unroll
        for (int dh = 0; dh < 3; ++dh)
            #pragma unroll
            for (int dw = 0; dw < 3; ++dw)
                s = fmaf(r[dh][i + dw], k9[dh*3 + dw], s);
        const float xc = r[1][i + 1];
        const float m = Gp[i];
        Op[i*64] = __float2bfloat16(leaky(leaky(s)*m + xc));
    }
}

// ---------------------------------------------------------------------------
// Dense 3x3 conv 64->64, implicit GEMM on MFMA bf16 — LDS-FREE version.
// Block 256 thr (4 waves) -> 16x16 px (M=256) x 64 oc. K = 18 x 32.
// A-fragments read directly from global NHWC (16B/lane, L1/L2-served;
// per-lane w-predication, wave-uniform h-predication). No barrier, no LDS
// -> occupancy VGPR-limited (4 waves/SIMD via launch_bounds).
// MODE 0: +leaky, NHWC bf16 out, + fused rda2 gate G2.
// MODE 1: +x residual, NCHW fp32 out.
// grid (64, B).
// ---------------------------------------------------------------------------
template<int MODE>
__global__ __launch_bounds__(256, 4) void k_conv_mfma(
    const __hip_bfloat16* __restrict__ Xn, const __hip_bfloat16* __restrict__ Wpk,
    const float* __restrict__ bias, const float* __restrict__ Xres,
    const float* __restrict__ Gcw, const float* __restrict__ Gcb,
    __hip_bfloat16* __restrict__ OutN, float* __restrict__ OutF,
    float* __restrict__ G2)
{
    const int tid = threadIdx.x;
    const int b = blockIdx.y;
    const int h0 = (blockIdx.x >> 3) * 16;
    const int w0 = (blockIdx.x & 7) * 16;

    const int lane = tid & 63;
    const int wv = tid >> 6;       // wave -> patch rows [wv*4, wv*4+4)
    const int l15 = lane & 15;
    const int lq = lane >> 4;

    float4v acc[4][4];
    #pragma unroll
    for (int i = 0; i < 4; ++i)
        #pragma unroll
        for (int j = 0; j < 4; ++j) acc[i][j] = (float4v)0.f;

    const short* Xs = (const short*)Xn;
    const short* Wp = (const short*)Wpk;
    const int gw_base = w0 + l15 - 1;      // + dwx

    #pragma unroll
    for (int s = 0; s < 18; ++s) {
        const int t = s >> 1, half = s & 1;
        const int dh = t / 3, dwx = t % 3;
        short8 afr[4], bfr[4];
        #pragma unroll
        for (int mt = 0; mt < 4; ++mt) {
            const int gh = h0 + wv*4 + mt + dh - 1;
            const int gw = gw_base + dwx;
            short8 a = (short8)(short)0;
            if ((unsigned)gh < (unsigned)H_ && (unsigned)gw < (unsigned)W_)
                a = *(const short8*)(Xs + (((size_t)b*H_ + gh)*W_ + gw)*64
                                        + half*32 + lq*8);
            afr[mt] = a;
        }
        #pragma unroll
        for (int nt = 0; nt < 4; ++nt)
            bfr[nt] = *(const short8*)(Wp + ((size_t)s*2048 + (nt*16 + l15)*32 + lq*8));
        #pragma unroll
        for (int mt = 0; mt < 4; ++mt)
            #pragma unroll
            for (int nt = 0; nt < 4; ++nt)
                acc[mt][nt] = __builtin_amdgcn_mfma_f32_16x16x32_bf16(
                    afr[mt], bfr[nt], acc[mt][nt], 0, 0, 0);
    }

    // ---- epilogue
    float bs[4], cwv[4], cbv = 0.f;
    #pragma unroll
    for (int nt = 0; nt < 4; ++nt) bs[nt] = bias[nt*16 + l15];
    if (MODE == 0) {
        #pragma unroll
        for (int nt = 0; nt < 4; ++nt) cwv[nt] = Gcw[nt*16 + l15];
        cbv = Gcb[0];
    }

    #pragma unroll
    for (int mt = 0; mt < 4; ++mt) {
        const int pr = wv*4 + mt;
        if (MODE == 0) {
            float vv[4][4];
            #pragma unroll
            for (int nt = 0; nt < 4; ++nt)
                #pragma unroll
                for (int rg = 0; rg < 4; ++rg)
                    vv[nt][rg] = leaky(acc[mt][nt][rg] + bs[nt]);
            #pragma unroll
            for (int nt = 0; nt < 4; ++nt) {
                const int n = nt*16 + l15;
                #pragma unroll
                for (int rg = 0; rg < 4; ++rg) {
                    const int pw = lq*4 + rg;
                    OutN[(((size_t)b*H_ + h0 + pr)*W_ + w0 + pw)*64 + n] =
                        __float2bfloat16(vv[nt][rg]);
                }
            }
            #pragma unroll
            for (int rg = 0; rg < 4; ++rg) {
                float p = vv[0][rg]*cwv[0] + vv[1][rg]*cwv[1]
                        + vv[2][rg]*cwv[2] + vv[3][rg]*cwv[3];
                p += __shfl_xor(p, 1);
                p += __shfl_xor(p, 2);
                p += __shfl_xor(p, 4);
                p += __shfl_xor(p, 8);
                if (l15 == 0)
                    G2[(size_t)b*HW_ + (size_t)(h0 + pr)*W_ + w0 + lq*4 + rg] =
                        1.f / (1.f + __expf(-(p + cbv)));
            }
        } else {
            #pragma unroll
            for (int nt = 0; nt < 4; ++nt) {
                const int n = nt*16 + l15;
                const size_t base = ((size_t)(b*64 + n)*H_ + h0 + pr)*W_ + w0 + lq*4;
                const float4 xr = *(const float4*)(Xres + base);
                float4 v;
                v.x = acc[mt][nt][0] + bs[nt] + xr.x;
                v.y = acc[mt][nt][1] + bs[nt] + xr.y;
                v.z = acc[mt][nt][2] + bs[nt] + xr.z;
                v.w = acc[mt][nt][3] + bs[nt] + xr.w;
                *(float4*)(OutF + base) = v;
            }
        }
    }
}

// ---------------------------------------------------------------------------
extern "C" void kernel_launch(void* const* d_in, const int* in_sizes, int n_in,
                              void* d_out, int out_size, void* d_ws, size_t ws_size,
                              hipStream_t stream)
{
    const float* x       = (const float*)d_in[0];
    const float* d       = (const float*)d_in[1];
    const float* da1_k1  = (const float*)d_in[2];
    const float* da1_k2  = (const float*)d_in[3];
    const float* da1_cw  = (const float*)d_in[4];
    const float* da1_cb  = (const float*)d_in[5];
    const float* da2_k1  = (const float*)d_in[6];
    const float* da2_k2  = (const float*)d_in[7];
    const float* da2_cw  = (const float*)d_in[8];
    const float* da2_cb  = (const float*)d_in[9];
    const float* conv1_w = (const float*)d_in[10];
    const float* conv1_b = (const float*)d_in[11];
    const float* conv2_w = (const float*)d_in[12];
    const float* conv2_b = (const float*)d_in[13];
    float* out = (float*)d_out;

    __hip_bfloat16* bufA = (__hip_bfloat16*)d_ws;      // NTOT_ bf16
    __hip_bfloat16* bufB = bufA + NTOT_;               // NTOT_ bf16
    float* kernA = (float*)(bufB + NTOT_);             // 16*576 fp32
    float* kernB = kernA + 16*576;
    __hip_bfloat16* wpk1 = (__hip_bfloat16*)(kernB + 16*576);  // 18*64*32
    __hip_bfloat16* wpk2 = wpk1 + 18*64*32;
    float* G1 = (float*)(wpk2 + 18*64*32);             // B*HW fp32
    float* G2 = G1 + (size_t)B_*HW_;                   // B*HW fp32

    k_dyn<<<dim3(96), dim3(192), 0, stream>>>(d, da1_k1, da1_k2, da2_k1, da2_k2,
                                              kernA, kernB);
    k_prepw<<<dim3(18, 2), dim3(256), 0, stream>>>(conv1_w, conv2_w, wpk1, wpk2);
    // pre + rda1 gate
    k_pre<<<dim3(HW_/64, B_), dim3(256), 0, stream>>>(x, da1_cw, da1_cb, bufA, G1);
    // rda1: bufA -> bufB
    k_rda_nhwc<<<dim3(B_*HW_/32), dim3(256), 0, stream>>>(bufA, kernA, G1, bufB);
    // conv1 (+leaky, + rda2 gate): bufB -> bufA (NHWC bf16), G2
    k_conv_mfma<0><<<dim3(64, B_), dim3(256), 0, stream>>>(
        bufB, wpk1, conv1_b, nullptr, da2_cw, da2_cb, bufA, nullptr, G2);
    // rda2: bufA -> bufB
    k_rda_nhwc<<<dim3(B_*HW_/32), dim3(256), 0, stream>>>(bufA, kernB, G2, bufB);
    // conv2 + x residual -> out (NCHW fp32)
    k_conv_mfma<1><<<dim3(64, B_), dim3(256), 0, stream>>>(
        bufB, wpk2, conv2_b, x, nullptr, nullptr, nullptr, out, nullptr);
}

// Round 6
// 326.974 us; speedup vs baseline: 1.2964x; 1.2964x over previous
//
#include <hip/hip_runtime.h>
#include <hip/hip_bf16.h>
#include <math.h>

#define B_ 16
#define C_ 64
#define H_ 128
#define W_ 128
#define HW_ (H_*W_)
#define CHW_ (C_*HW_)
#define NTOT_ (B_*CHW_)

typedef __attribute__((ext_vector_type(8))) short short8;
typedef __attribute__((ext_vector_type(4))) float float4v;

__device__ __forceinline__ float leaky(float v) { return v > 0.f ? v : 0.1f * v; }
__device__ __forceinline__ float b2f(__hip_bfloat16 h) { return __bfloat162float(h); }

// ---------------------------------------------------------------------------
// Dynamic kernel MLPs, wide: 96 blocks (2 which x 16 b x 3 chunks of 192).
// out layout: kern[b][t][c] for lane=c access in k_rda.
// ---------------------------------------------------------------------------
__global__ __launch_bounds__(192) void k_dyn(
    const float* __restrict__ d,
    const float* __restrict__ k1a, const float* __restrict__ k2a,
    const float* __restrict__ k1b, const float* __restrict__ k2b,
    float* __restrict__ kernA, float* __restrict__ kernB)
{
    const int which = blockIdx.x / 48;
    const int r     = blockIdx.x % 48;
    const int b     = r / 3;
    const int chunk = r % 3;
    const float* k1 = which ? k1b : k1a;
    const float* k2 = which ? k2b : k2a;
    float* outp = which ? kernB : kernA;

    __shared__ float hid[64];
    const int tid = threadIdx.x;
    if (tid < 64) {
        float s = 0.f;
        #pragma unroll
        for (int i = 0; i < 64; ++i) s = fmaf(d[b*64 + i], k1[i*64 + tid], s);
        hid[tid] = leaky(s);
    }
    __syncthreads();
    const int o = chunk * 192 + tid;       // 0..575
    float s = 0.f;
    #pragma unroll
    for (int j = 0; j < 64; ++j) s = fmaf(hid[j], k2[j*576 + o], s);
    outp[b*576 + (o % 9)*64 + (o / 9)] = s;
}

// ---------------------------------------------------------------------------
// Prepack conv weights: Wpk[s][oc][kk] bf16, s = t*2 + half, k = half*32+kk.
// ---------------------------------------------------------------------------
__global__ void k_prepw(const float* __restrict__ W1, const float* __restrict__ W2,
                        __hip_bfloat16* __restrict__ P1, __hip_bfloat16* __restrict__ P2)
{
    const int s = blockIdx.x;      // 0..17
    const int which = blockIdx.y;  // 0..1
    const float* W = which ? W2 : W1;
    __hip_bfloat16* P = which ? P2 : P1;
    const int t = s >> 1, half = s & 1;
    for (int idx = threadIdx.x; idx < 2048; idx += 256) {
        const int oc = idx >> 5, kk = idx & 31;
        P[s*2048 + idx] = __float2bfloat16(W[oc*576 + (half*32 + kk)*9 + t]);
    }
}

// ---------------------------------------------------------------------------
// NCHW fp32 -> NHWC bf16 + fused rda1 gate: G1[p] = sigmoid(sum_c x*cw + cb).
// grid (HW/64, B), block 256.
// ---------------------------------------------------------------------------
__global__ __launch_bounds__(256) void k_pre(const float* __restrict__ X,
                                             const float* __restrict__ cw,
                                             const float* __restrict__ cb,
                                             __hip_bfloat16* __restrict__ Xn,
                                             float* __restrict__ G1)
{
    __shared__ float sT[64][65];
    __shared__ float pG[4][64];
    const int b = blockIdx.y;
    const int p0 = blockIdx.x * 64;
    const int tid = threadIdx.x;
    #pragma unroll
    for (int i = 0; i < 16; ++i) {
        int idx = i*256 + tid;
        int c = idx >> 6, p = idx & 63;
        sT[c][p] = X[(size_t)b*CHW_ + (size_t)c*HW_ + p0 + p];
    }
    __syncthreads();
    #pragma unroll
    for (int i = 0; i < 16; ++i) {
        int idx = i*256 + tid;
        int p = idx >> 6, c = idx & 63;
        Xn[((size_t)b*HW_ + p0 + p)*64 + c] = __float2bfloat16(sT[c][p]);
    }
    const int cg = tid >> 6, p = tid & 63;
    float part = 0.f;
    #pragma unroll
    for (int c = 0; c < 16; ++c) part = fmaf(sT[cg*16 + c][p], cw[cg*16 + c], part);
    pG[cg][p] = part;
    __syncthreads();
    if (tid < 64) {
        float g = pG[0][tid] + pG[1][tid] + pG[2][tid] + pG[3][tid] + cb[0];
        G1[(size_t)b*HW_ + p0 + tid] = 1.f / (1.f + __expf(-g));
    }
}

// ---------------------------------------------------------------------------
// Fused RDA in NHWC, rolling-window. lane = channel; wave = 8 px row segment.
// out = leaky( leaky(dw3x3(X)) * G + X ).  grid = B*HW/32 blocks of 256.
// ---------------------------------------------------------------------------
__global__ __launch_bounds__(256) void k_rda_nhwc(
    const __hip_bfloat16* __restrict__ Xn, const float* __restrict__ kernN,
    const float* __restrict__ G, __hip_bfloat16* __restrict__ Out)
{
    const int lane = threadIdx.x & 63;
    const int wv = threadIdx.x >> 6;
    const int gid = blockIdx.x * 4 + wv;
    const int b = gid >> 11;
    const int rem = gid & 2047;
    const int h = rem >> 4;
    const int w0 = (rem & 15) * 8;

    float k9[9];
    #pragma unroll
    for (int t = 0; t < 9; ++t) k9[t] = kernN[((size_t)b*9 + t)*64 + lane];

    const __hip_bfloat16* Xb = Xn + (size_t)b * HW_ * 64 + lane;
    float r[3][10];
    #pragma unroll
    for (int dh = 0; dh < 3; ++dh) {
        const int hh = h - 1 + dh;
        if ((unsigned)hh < (unsigned)H_) {
            const __hip_bfloat16* rp = Xb + ((size_t)hh*W_ + w0) * 64;
            r[dh][0] = (w0 > 0) ? b2f(rp[-64]) : 0.f;
            #pragma unroll
            for (int j = 1; j < 9; ++j) r[dh][j] = b2f(rp[(j-1)*64]);
            r[dh][9] = (w0 + 8 < W_) ? b2f(rp[8*64]) : 0.f;
        } else {
            #pragma unroll
            for (int j = 0; j < 10; ++j) r[dh][j] = 0.f;
        }
    }

    const float* Gp = G + (size_t)b*HW_ + (size_t)h*W_ + w0;
    __hip_bfloat16* Op = Out + ((size_t)b*HW_ + (size_t)h*W_ + w0)*64 + lane;
    #pragma unroll
    for (int i = 0; i < 8; ++i) {
        float s = 0.f;
        #pragma unroll
        for (int dh = 0; dh < 3; ++dh)
            #pragma unroll
            for (int dw = 0; dw < 3; ++dw)
                s = fmaf(r[dh][i + dw], k9[dh*3 + dw], s);
        const float xc = r[1][i + 1];
        const float m = Gp[i];
        Op[i*64] = __float2bfloat16(leaky(leaky(s)*m + xc));
    }
}

// ---------------------------------------------------------------------------
// Dense 3x3 conv 64->64, implicit GEMM on MFMA bf16 — K-SPLIT LDS version.
// Block 256 thr (4 waves) -> 16x16 px (M=256) x 64 oc.  K = 576 split into
// two ic-halves of 32ch: stage 18x18x32 halo (20.7 KB LDS) -> 4 blocks/CU
// (VGPR-limited, 16 waves/CU) vs 3 with the full 41.5 KB tile.  Chunk-XOR
// swizzle g^((w>>1)&3): fragment reads are 2-way bank-aliased (free, m136).
// MODE 0: +leaky, NHWC bf16 out, + fused rda2 gate G2.
// MODE 1: +x residual, NCHW fp32 out.   grid (64, B).
// ---------------------------------------------------------------------------
template<int MODE>
__global__ __launch_bounds__(256, 4) void k_conv_mfma(
    const __hip_bfloat16* __restrict__ Xn, const __hip_bfloat16* __restrict__ Wpk,
    const float* __restrict__ bias, const float* __restrict__ Xres,
    const float* __restrict__ Gcw, const float* __restrict__ Gcb,
    __hip_bfloat16* __restrict__ OutN, float* __restrict__ OutF,
    float* __restrict__ G2)
{
    __shared__ short sA[18*18*32];   // 20736 B
    const int tid = threadIdx.x;
    const int b = blockIdx.y;
    const int h0 = (blockIdx.x >> 3) * 16;
    const int w0 = (blockIdx.x & 7) * 16;

    const int lane = tid & 63;
    const int wv = tid >> 6;       // wave -> patch rows [wv*4, wv*4+4)
    const int l15 = lane & 15;
    const int lq = lane >> 4;

    float4v acc[4][4];
    #pragma unroll
    for (int i = 0; i < 4; ++i)
        #pragma unroll
        for (int j = 0; j < 4; ++j) acc[i][j] = (float4v)0.f;

    const short* Xs = (const short*)Xn;
    const short* Wp = (const short*)Wpk;

    #pragma unroll
    for (int half = 0; half < 2; ++half) {
        if (half) __syncthreads();       // all waves done reading previous half
        // ---- stage 18x18 halo, 32 channels (4 granules of 16B per px)
        for (int idx = tid; idx < 1296; idx += 256) {
            const int r = idx / 72;
            const int rem = idx - r * 72;
            const int w = rem >> 2;
            const int g = rem & 3;
            const int gh = h0 - 1 + r;
            const int gw = w0 - 1 + w;
            uint4 v = make_uint4(0, 0, 0, 0);
            if ((unsigned)gh < (unsigned)H_ && (unsigned)gw < (unsigned)W_)
                v = *(const uint4*)(Xs + (((size_t)b*H_ + gh)*W_ + gw)*64
                                        + half*32 + g*8);
            *(uint4*)(sA + ((r*18 + w)*32 + (g ^ ((w >> 1) & 3))*8)) = v;
        }
        __syncthreads();

        #pragma unroll
        for (int t = 0; t < 9; ++t) {
            const int s = t*2 + half;
            const int dh = t / 3, dwx = t % 3;
            short8 afr[4], bfr[4];
            #pragma unroll
            for (int mt = 0; mt < 4; ++mt) {
                const int r = wv*4 + mt + dh;
                const int w = l15 + dwx;
                const int chunk = lq ^ ((w >> 1) & 3);
                afr[mt] = *(const short8*)(sA + ((r*18 + w)*32 + chunk*8));
            }
            #pragma unroll
            for (int nt = 0; nt < 4; ++nt)
                bfr[nt] = *(const short8*)(Wp + ((size_t)s*2048 + (nt*16 + l15)*32 + lq*8));
            #pragma unroll
            for (int mt = 0; mt < 4; ++mt)
                #pragma unroll
                for (int nt = 0; nt < 4; ++nt)
                    acc[mt][nt] = __builtin_amdgcn_mfma_f32_16x16x32_bf16(
                        afr[mt], bfr[nt], acc[mt][nt], 0, 0, 0);
        }
    }

    // ---- epilogue
    float bs[4], cwv[4], cbv = 0.f;
    #pragma unroll
    for (int nt = 0; nt < 4; ++nt) bs[nt] = bias[nt*16 + l15];
    if (MODE == 0) {
        #pragma unroll
        for (int nt = 0; nt < 4; ++nt) cwv[nt] = Gcw[nt*16 + l15];
        cbv = Gcb[0];
    }

    #pragma unroll
    for (int mt = 0; mt < 4; ++mt) {
        const int pr = wv*4 + mt;
        if (MODE == 0) {
            float vv[4][4];
            #pragma unroll
            for (int nt = 0; nt < 4; ++nt)
                #pragma unroll
                for (int rg = 0; rg < 4; ++rg)
                    vv[nt][rg] = leaky(acc[mt][nt][rg] + bs[nt]);
            #pragma unroll
            for (int nt = 0; nt < 4; ++nt) {
                const int n = nt*16 + l15;
                #pragma unroll
                for (int rg = 0; rg < 4; ++rg) {
                    const int pw = lq*4 + rg;
                    OutN[(((size_t)b*H_ + h0 + pr)*W_ + w0 + pw)*64 + n] =
                        __float2bfloat16(vv[nt][rg]);
                }
            }
            #pragma unroll
            for (int rg = 0; rg < 4; ++rg) {
                float p = vv[0][rg]*cwv[0] + vv[1][rg]*cwv[1]
                        + vv[2][rg]*cwv[2] + vv[3][rg]*cwv[3];
                p += __shfl_xor(p, 1);
                p += __shfl_xor(p, 2);
                p += __shfl_xor(p, 4);
                p += __shfl_xor(p, 8);
                if (l15 == 0)
                    G2[(size_t)b*HW_ + (size_t)(h0 + pr)*W_ + w0 + lq*4 + rg] =
                        1.f / (1.f + __expf(-(p + cbv)));
            }
        } else {
            #pragma unroll
            for (int nt = 0; nt < 4; ++nt) {
                const int n = nt*16 + l15;
                const size_t base = ((size_t)(b*64 + n)*H_ + h0 + pr)*W_ + w0 + lq*4;
                const float4 xr = *(const float4*)(Xres + base);
                float4 v;
                v.x = acc[mt][nt][0] + bs[nt] + xr.x;
                v.y = acc[mt][nt][1] + bs[nt] + xr.y;
                v.z = acc[mt][nt][2] + bs[nt] + xr.z;
                v.w = acc[mt][nt][3] + bs[nt] + xr.w;
                *(float4*)(OutF + base) = v;
            }
        }
    }
}

// ---------------------------------------------------------------------------
extern "C" void kernel_launch(void* const* d_in, const int* in_sizes, int n_in,
                              void* d_out, int out_size, void* d_ws, size_t ws_size,
                              hipStream_t stream)
{
    const float* x       = (const float*)d_in[0];
    const float* d       = (const float*)d_in[1];
    const float* da1_k1  = (const float*)d_in[2];
    const float* da1_k2  = (const float*)d_in[3];
    const float* da1_cw  = (const float*)d_in[4];
    const float* da1_cb  = (const float*)d_in[5];
    const float* da2_k1  = (const float*)d_in[6];
    const float* da2_k2  = (const float*)d_in[7];
    const float* da2_cw  = (const float*)d_in[8];
    const float* da2_cb  = (const float*)d_in[9];
    const float* conv1_w = (const float*)d_in[10];
    const float* conv1_b = (const float*)d_in[11];
    const float* conv2_w = (const float*)d_in[12];
    const float* conv2_b = (const float*)d_in[13];
    float* out = (float*)d_out;

    __hip_bfloat16* bufA = (__hip_bfloat16*)d_ws;      // NTOT_ bf16
    __hip_bfloat16* bufB = bufA + NTOT_;               // NTOT_ bf16
    float* kernA = (float*)(bufB + NTOT_);             // 16*576 fp32
    float* kernB = kernA + 16*576;
    __hip_bfloat16* wpk1 = (__hip_bfloat16*)(kernB + 16*576);  // 18*64*32
    __hip_bfloat16* wpk2 = wpk1 + 18*64*32;
    float* G1 = (float*)(wpk2 + 18*64*32);             // B*HW fp32
    float* G2 = G1 + (size_t)B_*HW_;                   // B*HW fp32

    k_dyn<<<dim3(96), dim3(192), 0, stream>>>(d, da1_k1, da1_k2, da2_k1, da2_k2,
                                              kernA, kernB);
    k_prepw<<<dim3(18, 2), dim3(256), 0, stream>>>(conv1_w, conv2_w, wpk1, wpk2);
    // pre + rda1 gate
    k_pre<<<dim3(HW_/64, B_), dim3(256), 0, stream>>>(x, da1_cw, da1_cb, bufA, G1);
    // rda1: bufA -> bufB
    k_rda_nhwc<<<dim3(B_*HW_/32), dim3(256), 0, stream>>>(bufA, kernA, G1, bufB);
    // conv1 (+leaky, + rda2 gate): bufB -> bufA (NHWC bf16), G2
    k_conv_mfma<0><<<dim3(64, B_), dim3(256), 0, stream>>>(
        bufB, wpk1, conv1_b, nullptr, da2_cw, da2_cb, bufA, nullptr, G2);
    // rda2: bufA -> bufB
    k_rda_nhwc<<<dim3(B_*HW_/32), dim3(256), 0, stream>>>(bufA, kernB, G2, bufB);
    // conv2 + x residual -> out (NCHW fp32)
    k_conv_mfma<1><<<dim3(64, B_), dim3(256), 0, stream>>>(
        bufB, wpk2, conv2_b, x, nullptr, nullptr, nullptr, out, nullptr);
}